// Round 5
// baseline (340.001 us; speedup 1.0000x reference)
//
#include <hip/hip_runtime.h>

#define N_NODES 10000
#define HID 512
#define MPAD 10112          // 158 * 64
#define N_GRAPHS 64
#define N_CLASSES 10

typedef __bf16 bf16_t;
typedef __bf16 bf16x2 __attribute__((ext_vector_type(2)));
typedef __bf16 bf16x8 __attribute__((ext_vector_type(8)));
typedef float  f32x4  __attribute__((ext_vector_type(4)));

// ---------------------------------------------------------------------------
// async global->LDS 16B copy (gfx950). LDS dest is wave-uniform base + lane*16;
// our chunk->thread mapping is linear so per-lane dst pointers satisfy that.
// ---------------------------------------------------------------------------
__device__ __forceinline__ void gload16(const bf16_t* g, bf16_t* l) {
    __builtin_amdgcn_global_load_lds(
        (const __attribute__((address_space(1))) void*)g,
        (__attribute__((address_space(3))) void*)l,
        16, 0, 0);
}

// ---------------------------------------------------------------------------
// zero_k: replaces 5 hipMemsetAsync (cnt, cur, xh-pad, xl-pad; pooled removed)
// ---------------------------------------------------------------------------
__global__ void zero_k(int* __restrict__ cnt, int* __restrict__ cur,
                       bf16_t* __restrict__ xh_pad, bf16_t* __restrict__ xl_pad) {
    int i = blockIdx.x * 256 + threadIdx.x;          // grid 40*256 = 10240
    if (i < N_NODES) { cnt[i] = 0; cur[i] = 0; }
    const int PCH = (MPAD - N_NODES) * HID / 8;      // 7168 16B-chunks
    if (i < PCH) {
        uint4 z = {0, 0, 0, 0};
        *(uint4*)&xh_pad[i * 8] = z;
        *(uint4*)&xl_pad[i * 8] = z;
    }
}

// ---------------------------------------------------------------------------
// Input conversion: x (fp32) -> bf16 hi/lo pair (3-term split GEMM precision)
// ---------------------------------------------------------------------------
__global__ void conv_x(const float* __restrict__ x,
                       bf16_t* __restrict__ xh, bf16_t* __restrict__ xl) {
    int idx = (blockIdx.x * 256 + threadIdx.x) * 8;   // < N_NODES*HID
    f32x4 v0 = *(const f32x4*)&x[idx];
    f32x4 v1 = *(const f32x4*)&x[idx + 4];
    float v[8] = {v0[0], v0[1], v0[2], v0[3], v1[0], v1[1], v1[2], v1[3]};
    bf16x8 hi, lo;
#pragma unroll
    for (int j = 0; j < 8; ++j) {
        bf16_t h = (bf16_t)v[j];
        hi[j] = h;
        lo[j] = (bf16_t)(v[j] - (float)h);
    }
    *(bf16x8*)&xh[idx] = hi;
    *(bf16x8*)&xl[idx] = lo;
}

// W [3][512][512] row-major (W[l][k][j]) -> transposed bf16 hi/lo: WT[l][j][k]
__global__ void conv_w(const float* __restrict__ W,
                       bf16_t* __restrict__ whT, bf16_t* __restrict__ wlT) {
    int o   = blockIdx.x * 256 + threadIdx.x;  // < 3*512*512, output-indexed
    int lyr = o >> 18;
    int rem = o & 262143;
    int j   = rem >> 9;
    int k   = rem & 511;
    float v = W[(lyr << 18) + (k << 9) + j];
    bf16_t h = (bf16_t)v;
    whT[o] = h;
    wlT[o] = (bf16_t)(v - (float)h);
}

// ---------------------------------------------------------------------------
// Degree + CSR build (grouped by target col), no fp32 atomics in hot path
// ---------------------------------------------------------------------------
__global__ void count_deg(const int* __restrict__ col, int* __restrict__ cnt, int E) {
    int e = blockIdx.x * 256 + threadIdx.x;
    if (e < E) atomicAdd(&cnt[col[e]], 1);
}

// scan (exclusive prefix over cnt -> off) + dinv fused (reads cnt anyway)
__global__ __launch_bounds__(1024) void scan_k(const int* __restrict__ cnt,
                                               int* __restrict__ off,
                                               float* __restrict__ dinv) {
    __shared__ int s[1024];
    int t = threadIdx.x;
    int base = t * 10;
    int loc[10];
    int sum = 0;
#pragma unroll
    for (int j = 0; j < 10; ++j) {
        int n = base + j;
        int v = (n < N_NODES) ? cnt[n] : 0;
        if (n < N_NODES) dinv[n] = rsqrtf(1.0f + (float)v);  // +1 self-loop
        loc[j] = sum;
        sum += v;
    }
    s[t] = sum;
    __syncthreads();
    for (int o = 1; o < 1024; o <<= 1) {
        int v = (t >= o) ? s[t - o] : 0;
        __syncthreads();
        s[t] += v;
        __syncthreads();
    }
    int pre = (t > 0) ? s[t - 1] : 0;
#pragma unroll
    for (int j = 0; j < 10; ++j) {
        int n = base + j;
        if (n <= N_NODES) off[n] = pre + loc[j];
    }
}

// packed edge record: .x = src index, .y = float bits of weight
__global__ void scatter_k(const int* __restrict__ row, const int* __restrict__ col,
                          const int* __restrict__ off, int* __restrict__ cursor,
                          const float* __restrict__ dinv,
                          int2* __restrict__ epk, int E) {
    int e = blockIdx.x * 256 + threadIdx.x;
    if (e >= E) return;
    int c = col[e], r = row[e];
    int p = off[c] + atomicAdd(&cursor[c], 1);
    float w = dinv[r] * dinv[c];
    epk[p] = make_int2(r, __float_as_int(w));
}

// ---------------------------------------------------------------------------
// GEMM: hh[MPAD][512] = bf16( (xh+xl) @ (Wh+Wl) )  via 3-term bf16 MFMA split
// 64x128 tile, 4 waves (2x2), 32x64/wave, BK=32, global_load_lds staging.
// (unchanged from round 3 — control)
// ---------------------------------------------------------------------------
__global__ __launch_bounds__(256) void gemm3(
    const bf16_t* __restrict__ xh, const bf16_t* __restrict__ xl,
    const bf16_t* __restrict__ wh, const bf16_t* __restrict__ wl,  // [512][512] = W^T[j][k]
    bf16_t* __restrict__ hh)
{
    __shared__ alignas(16) bf16_t sAh[64 * 32];
    __shared__ alignas(16) bf16_t sAl[64 * 32];
    __shared__ alignas(16) bf16_t sBh[128 * 32];
    __shared__ alignas(16) bf16_t sBl[128 * 32];

    const int t  = threadIdx.x;
    const int l  = t & 63;
    const int wv = t >> 6;
    const int wr = wv >> 1;   // 0..1: 32-row half of M-tile
    const int wc = wv & 1;    // 0..1: 64-col half of N-tile
    const int n0 = blockIdx.x * 128;
    const int m0 = blockIdx.y * 64;

    f32x4 acc[2][4];
#pragma unroll
    for (int m = 0; m < 2; ++m)
#pragma unroll
        for (int n = 0; n < 4; ++n) acc[m][n] = (f32x4){0.f, 0.f, 0.f, 0.f};

    const int lr  = l & 15;
    const int kgr = (l >> 4) * 8;        // k-group start within BK=32
    const int srow = t >> 2;             // staging row 0..63
    const int sce  = (t & 3) * 8;        // staging element offset within row

    for (int kk = 0; kk < HID; kk += 32) {
        __syncthreads();  // previous iter's readers done before overwrite
        {
            size_t gA  = (size_t)(m0 + srow) * HID + kk + sce;
            size_t gB0 = (size_t)(n0 + srow) * HID + kk + sce;
            size_t gB1 = (size_t)(n0 + 64 + srow) * HID + kk + sce;
            gload16(&xh[gA],  &sAh[t * 8]);
            gload16(&xl[gA],  &sAl[t * 8]);
            gload16(&wh[gB0], &sBh[t * 8]);
            gload16(&wl[gB0], &sBl[t * 8]);
            gload16(&wh[gB1], &sBh[(t + 256) * 8]);
            gload16(&wl[gB1], &sBl[(t + 256) * 8]);
        }
        __syncthreads();

        bf16x8 ah[2], al[2], bh[4], bl[4];
#pragma unroll
        for (int m = 0; m < 2; ++m) {
            int row = wr * 32 + m * 16 + lr;
            ah[m] = *(const bf16x8*)&sAh[row * 32 + kgr];
            al[m] = *(const bf16x8*)&sAl[row * 32 + kgr];
        }
#pragma unroll
        for (int n = 0; n < 4; ++n) {
            int col = wc * 64 + n * 16 + lr;
            bh[n] = *(const bf16x8*)&sBh[col * 32 + kgr];
            bl[n] = *(const bf16x8*)&sBl[col * 32 + kgr];
        }
#pragma unroll
        for (int m = 0; m < 2; ++m)
#pragma unroll
            for (int n = 0; n < 4; ++n) {
                acc[m][n] = __builtin_amdgcn_mfma_f32_16x16x32_bf16(ah[m], bh[n], acc[m][n], 0, 0, 0);
                acc[m][n] = __builtin_amdgcn_mfma_f32_16x16x32_bf16(al[m], bh[n], acc[m][n], 0, 0, 0);
                acc[m][n] = __builtin_amdgcn_mfma_f32_16x16x32_bf16(ah[m], bl[n], acc[m][n], 0, 0, 0);
            }
    }

    // C/D layout (m89-verified): col = l&15, row = (l>>4)*4 + r
    const int rq = (l >> 4) * 4;
#pragma unroll
    for (int m = 0; m < 2; ++m) {
        int row = m0 + wr * 32 + m * 16 + rq;
#pragma unroll
        for (int n = 0; n < 4; ++n) {
            int col = n0 + wc * 64 + n * 16 + lr;
#pragma unroll
            for (int r = 0; r < 4; ++r)
                hh[(size_t)(row + r) * HID + col] = (bf16_t)acc[m][n][r];
        }
    }
}

// ---------------------------------------------------------------------------
// Aggregation, XCD-sliced: feature cols split into 4 slices of 128.
// slice = blockIdx.x & 3; dispatch round-robins XCDs (wg i -> XCD i%8), so
// XCD x only touches slice x%4 (2.6 MB of hh) -> L2-resident gather.
// One wave per (node, slice); lane owns 2 cols (bf16x2 load per edge row).
// ---------------------------------------------------------------------------
template <bool LAST>
__global__ __launch_bounds__(256) void agg_k(
    const bf16_t* __restrict__ hh, const int* __restrict__ off,
    const int2* __restrict__ epk,
    const float* __restrict__ dinv, const float* __restrict__ bias,
    bf16_t* __restrict__ xh, bf16_t* __restrict__ xl, float* __restrict__ x3)
{
    int b     = blockIdx.x;                         // 0..9999
    int slice = b & 3;
    int node  = (b >> 2) * 4 + (threadIdx.x >> 6);  // N_NODES % 4 == 0
    int l     = threadIdx.x & 63;
    int c0    = slice * 128 + l * 2;

    float dn = dinv[node];
    float sw = dn * dn;
    float a0, a1;
    {
        bf16x2 sv = *(const bf16x2*)&hh[(size_t)node * HID + c0];
        a0 = (float)sv[0] * sw;
        a1 = (float)sv[1] * sw;
    }

    int e0 = off[node], e1 = off[node + 1];
    for (int e = e0; e < e1; ++e) {
        int2 ed = epk[e];
        float w = __int_as_float(ed.y);
        bf16x2 v = *(const bf16x2*)&hh[(size_t)ed.x * HID + c0];
        a0 += (float)v[0] * w;
        a1 += (float)v[1] * w;
    }
    float2 bb = *(const float2*)&bias[c0];
    a0 += bb.x;
    a1 += bb.y;
    if (a0 < 0.f) a0 = 0.f;
    if (a1 < 0.f) a1 = 0.f;

    if (LAST) {
        float2 o = {a0, a1};
        *(float2*)&x3[(size_t)node * HID + c0] = o;
    } else {
        bf16_t h0 = (bf16_t)a0, h1 = (bf16_t)a1;
        bf16x2 hi = {h0, h1};
        bf16x2 lo = {(bf16_t)(a0 - (float)h0), (bf16_t)(a1 - (float)h1)};
        *(bf16x2*)&xh[(size_t)node * HID + c0] = hi;
        *(bf16x2*)&xl[(size_t)node * HID + c0] = lo;
    }
}

// ---------------------------------------------------------------------------
// Fused pool + head: block g sums its node range (batch sorted -> binary
// search), then computes logits + log_softmax for graph g. No atomics,
// no pooled roundtrip.
// ---------------------------------------------------------------------------
__global__ __launch_bounds__(256) void pool_head_k(
    const float* __restrict__ x3, const int* __restrict__ batch,
    const float* __restrict__ lw, const float* __restrict__ lb,
    float* __restrict__ out)
{
    __shared__ float sp[HID];
    __shared__ float slog[N_CLASSES];
    int g = blockIdx.x, t = threadIdx.x;

    int lo = 0, hi = N_NODES;
    while (lo < hi) { int mid = (lo + hi) >> 1; if (batch[mid] < g) lo = mid + 1; else hi = mid; }
    int ns = lo;
    hi = N_NODES;
    while (lo < hi) { int mid = (lo + hi) >> 1; if (batch[mid] < g + 1) lo = mid + 1; else hi = mid; }
    int ne = lo;

    float a0 = 0.f, a1 = 0.f;
    for (int n = ns; n < ne; ++n) {
        a0 += x3[(size_t)n * HID + t];
        a1 += x3[(size_t)n * HID + t + 256];
    }
    sp[t] = a0;
    sp[t + 256] = a1;
    __syncthreads();

    int wv = t >> 6, l = t & 63;
    for (int c = wv; c < N_CLASSES; c += 4) {
        float s = 0.f;
        for (int k = l; k < HID; k += 64) s += sp[k] * lw[k * N_CLASSES + c];
        for (int o = 32; o > 0; o >>= 1) s += __shfl_down(s, o);
        if (l == 0) slog[c] = s + lb[c];
    }
    __syncthreads();
    if (t == 0) {
        float mx = -1e30f;
#pragma unroll
        for (int c = 0; c < N_CLASSES; ++c) mx = fmaxf(mx, slog[c]);
        float se = 0.f;
#pragma unroll
        for (int c = 0; c < N_CLASSES; ++c) se += expf(slog[c] - mx);
        float lse = logf(se);
#pragma unroll
        for (int c = 0; c < N_CLASSES; ++c) out[g * N_CLASSES + c] = slog[c] - mx - lse;
    }
}

// ---------------------------------------------------------------------------
extern "C" void kernel_launch(void* const* d_in, const int* in_sizes, int n_in,
                              void* d_out, int out_size, void* d_ws, size_t ws_size,
                              hipStream_t stream) {
    const float* x     = (const float*)d_in[0];
    const int*   ei    = (const int*)d_in[1];
    const int*   batch = (const int*)d_in[2];
    const float* Ws    = (const float*)d_in[3];
    const float* bs    = (const float*)d_in[4];
    const float* lw    = (const float*)d_in[5];
    const float* lb    = (const float*)d_in[6];
    float*       out   = (float*)d_out;
    const int E = in_sizes[1] / 2;
    const int* erow = ei;       // edge_index[0] = source
    const int* ecol = ei + E;   // edge_index[1] = target (aggregation index)

    char* p = (char*)d_ws;
    auto take = [&](size_t bytes) {
        char* q = p;
        p += (bytes + 255) & ~(size_t)255;
        return q;
    };
    bf16_t* xh    = (bf16_t*)take((size_t)MPAD * HID * 2);
    bf16_t* xl    = (bf16_t*)take((size_t)MPAD * HID * 2);
    bf16_t* hh    = (bf16_t*)take((size_t)MPAD * HID * 2);
    float*  x3    = (float*) take((size_t)N_NODES * HID * 4);
    bf16_t* whT   = (bf16_t*)take((size_t)3 * HID * HID * 2);
    bf16_t* wlT   = (bf16_t*)take((size_t)3 * HID * HID * 2);
    float*  dinv  = (float*) take((size_t)N_NODES * 4);
    int*    cnt   = (int*)   take((size_t)N_NODES * 4);
    int*    off   = (int*)   take((size_t)(N_NODES + 1) * 4);
    int*    cur   = (int*)   take((size_t)N_NODES * 4);
    int2*   epk   = (int2*)  take((size_t)E * 8);

    zero_k<<<40, 256, 0, stream>>>(cnt, cur, xh + (size_t)N_NODES * HID,
                                   xl + (size_t)N_NODES * HID);
    conv_x<<<(N_NODES * HID) / (256 * 8), 256, 0, stream>>>(x, xh, xl);
    conv_w<<<(3 * HID * HID) / 256, 256, 0, stream>>>(Ws, whT, wlT);
    count_deg<<<(E + 255) / 256, 256, 0, stream>>>(ecol, cnt, E);
    scan_k<<<1, 1024, 0, stream>>>(cnt, off, dinv);
    scatter_k<<<(E + 255) / 256, 256, 0, stream>>>(erow, ecol, off, cur, dinv, epk, E);

    for (int lyr = 0; lyr < 3; ++lyr) {
        gemm3<<<dim3(4, 158), 256, 0, stream>>>(
            xh, xl, whT + (size_t)lyr * HID * HID, wlT + (size_t)lyr * HID * HID, hh);
        if (lyr < 2)
            agg_k<false><<<(N_NODES / 4) * 4, 256, 0, stream>>>(
                hh, off, epk, dinv, bs + lyr * HID, xh, xl, nullptr);
        else
            agg_k<true><<<(N_NODES / 4) * 4, 256, 0, stream>>>(
                hh, off, epk, dinv, bs + lyr * HID, nullptr, nullptr, x3);
    }
    pool_head_k<<<N_GRAPHS, 256, 0, stream>>>(x3, batch, lw, lb, out);
}

// Round 6
// 245.655 us; speedup vs baseline: 1.3841x; 1.3841x over previous
//
#include <hip/hip_runtime.h>

#define N_NODES 10000
#define HID 512
#define MPAD 10112          // 158 * 64
#define N_GRAPHS 64
#define N_CLASSES 10

typedef __bf16 bf16_t;
typedef __bf16 bf16x8 __attribute__((ext_vector_type(8)));
typedef float  f32x4  __attribute__((ext_vector_type(4)));

// ---------------------------------------------------------------------------
// async global->LDS 16B copy (gfx950). LDS dest is wave-uniform base + lane*16;
// our chunk->thread mapping is linear so per-lane dst pointers satisfy that.
// ---------------------------------------------------------------------------
__device__ __forceinline__ void gload16(const bf16_t* g, bf16_t* l) {
    __builtin_amdgcn_global_load_lds(
        (const __attribute__((address_space(1))) void*)g,
        (__attribute__((address_space(3))) void*)l,
        16, 0, 0);
}

// ---------------------------------------------------------------------------
// zero_k: cnt, cur, xh/xl pad rows, pooled — one dispatch replaces 5 memsets
// ---------------------------------------------------------------------------
__global__ void zero_k(int* __restrict__ cnt, int* __restrict__ cur,
                       bf16_t* __restrict__ xh_pad, bf16_t* __restrict__ xl_pad,
                       float* __restrict__ pooled) {
    int i = blockIdx.x * 256 + threadIdx.x;          // grid 40*256 = 10240
    if (i < N_NODES) { cnt[i] = 0; cur[i] = 0; }
    const int PCH = (MPAD - N_NODES) * HID / 8;      // 7168 16B-chunks
    uint4 z = {0, 0, 0, 0};
    if (i < PCH) {
        *(uint4*)&xh_pad[i * 8] = z;
        *(uint4*)&xl_pad[i * 8] = z;
    }
    if (i < N_GRAPHS * HID / 4) *(uint4*)&pooled[i * 4] = z;
}

// ---------------------------------------------------------------------------
// Input conversion: x (fp32) -> bf16 hi/lo pair (3-term split GEMM precision)
// ---------------------------------------------------------------------------
__global__ void conv_x(const float* __restrict__ x,
                       bf16_t* __restrict__ xh, bf16_t* __restrict__ xl) {
    int idx = (blockIdx.x * 256 + threadIdx.x) * 8;   // < N_NODES*HID
    f32x4 v0 = *(const f32x4*)&x[idx];
    f32x4 v1 = *(const f32x4*)&x[idx + 4];
    float v[8] = {v0[0], v0[1], v0[2], v0[3], v1[0], v1[1], v1[2], v1[3]};
    bf16x8 hi, lo;
#pragma unroll
    for (int j = 0; j < 8; ++j) {
        bf16_t h = (bf16_t)v[j];
        hi[j] = h;
        lo[j] = (bf16_t)(v[j] - (float)h);
    }
    *(bf16x8*)&xh[idx] = hi;
    *(bf16x8*)&xl[idx] = lo;
}

// W [3][512][512] row-major (W[l][k][j]) -> transposed bf16 hi/lo: WT[l][j][k]
__global__ void conv_w(const float* __restrict__ W,
                       bf16_t* __restrict__ whT, bf16_t* __restrict__ wlT) {
    int o   = blockIdx.x * 256 + threadIdx.x;  // < 3*512*512, output-indexed
    int lyr = o >> 18;
    int rem = o & 262143;
    int j   = rem >> 9;
    int k   = rem & 511;
    float v = W[(lyr << 18) + (k << 9) + j];
    bf16_t h = (bf16_t)v;
    whT[o] = h;
    wlT[o] = (bf16_t)(v - (float)h);
}

// ---------------------------------------------------------------------------
// Degree + CSR build (grouped by target col), no fp32 atomics in hot path
// ---------------------------------------------------------------------------
__global__ void count_deg(const int* __restrict__ col, int* __restrict__ cnt, int E) {
    int e = blockIdx.x * 256 + threadIdx.x;
    if (e < E) atomicAdd(&cnt[col[e]], 1);
}

// scan (exclusive prefix over cnt -> off) + dinv fused (reads cnt anyway)
__global__ __launch_bounds__(1024) void scan_k(const int* __restrict__ cnt,
                                               int* __restrict__ off,
                                               float* __restrict__ dinv) {
    __shared__ int s[1024];
    int t = threadIdx.x;
    int base = t * 10;
    int loc[10];
    int sum = 0;
#pragma unroll
    for (int j = 0; j < 10; ++j) {
        int n = base + j;
        int v = (n < N_NODES) ? cnt[n] : 0;
        if (n < N_NODES) dinv[n] = rsqrtf(1.0f + (float)v);  // +1 self-loop
        loc[j] = sum;
        sum += v;
    }
    s[t] = sum;
    __syncthreads();
    for (int o = 1; o < 1024; o <<= 1) {
        int v = (t >= o) ? s[t - o] : 0;
        __syncthreads();
        s[t] += v;
        __syncthreads();
    }
    int pre = (t > 0) ? s[t - 1] : 0;
#pragma unroll
    for (int j = 0; j < 10; ++j) {
        int n = base + j;
        if (n <= N_NODES) off[n] = pre + loc[j];
    }
}

// packed edge record: .x = src index, .y = float bits of weight
__global__ void scatter_k(const int* __restrict__ row, const int* __restrict__ col,
                          const int* __restrict__ off, int* __restrict__ cursor,
                          const float* __restrict__ dinv,
                          int2* __restrict__ epk, int E) {
    int e = blockIdx.x * 256 + threadIdx.x;
    if (e >= E) return;
    int c = col[e], r = row[e];
    int p = off[c] + atomicAdd(&cursor[c], 1);
    float w = dinv[r] * dinv[c];
    epk[p] = make_int2(r, __float_as_int(w));
}

// ---------------------------------------------------------------------------
// GEMM: hh[MPAD][512] = bf16( (xh+xl) @ (Wh+Wl) )  via 3-term bf16 MFMA split
// 64x128 tile, 4 waves (2x2), 32x64/wave, BK=32, global_load_lds staging.
// ---------------------------------------------------------------------------
__global__ __launch_bounds__(256) void gemm3(
    const bf16_t* __restrict__ xh, const bf16_t* __restrict__ xl,
    const bf16_t* __restrict__ wh, const bf16_t* __restrict__ wl,  // [512][512] = W^T[j][k]
    bf16_t* __restrict__ hh)
{
    __shared__ alignas(16) bf16_t sAh[64 * 32];
    __shared__ alignas(16) bf16_t sAl[64 * 32];
    __shared__ alignas(16) bf16_t sBh[128 * 32];
    __shared__ alignas(16) bf16_t sBl[128 * 32];

    const int t  = threadIdx.x;
    const int l  = t & 63;
    const int wv = t >> 6;
    const int wr = wv >> 1;   // 0..1: 32-row half of M-tile
    const int wc = wv & 1;    // 0..1: 64-col half of N-tile
    const int n0 = blockIdx.x * 128;
    const int m0 = blockIdx.y * 64;

    f32x4 acc[2][4];
#pragma unroll
    for (int m = 0; m < 2; ++m)
#pragma unroll
        for (int n = 0; n < 4; ++n) acc[m][n] = (f32x4){0.f, 0.f, 0.f, 0.f};

    const int lr  = l & 15;
    const int kgr = (l >> 4) * 8;        // k-group start within BK=32
    const int srow = t >> 2;             // staging row 0..63
    const int sce  = (t & 3) * 8;        // staging element offset within row

    for (int kk = 0; kk < HID; kk += 32) {
        __syncthreads();  // previous iter's readers done before overwrite
        {
            size_t gA  = (size_t)(m0 + srow) * HID + kk + sce;
            size_t gB0 = (size_t)(n0 + srow) * HID + kk + sce;
            size_t gB1 = (size_t)(n0 + 64 + srow) * HID + kk + sce;
            gload16(&xh[gA],  &sAh[t * 8]);
            gload16(&xl[gA],  &sAl[t * 8]);
            gload16(&wh[gB0], &sBh[t * 8]);
            gload16(&wl[gB0], &sBl[t * 8]);
            gload16(&wh[gB1], &sBh[(t + 256) * 8]);
            gload16(&wl[gB1], &sBl[(t + 256) * 8]);
        }
        __syncthreads();

        bf16x8 ah[2], al[2], bh[4], bl[4];
#pragma unroll
        for (int m = 0; m < 2; ++m) {
            int row = wr * 32 + m * 16 + lr;
            ah[m] = *(const bf16x8*)&sAh[row * 32 + kgr];
            al[m] = *(const bf16x8*)&sAl[row * 32 + kgr];
        }
#pragma unroll
        for (int n = 0; n < 4; ++n) {
            int col = wc * 64 + n * 16 + lr;
            bh[n] = *(const bf16x8*)&sBh[col * 32 + kgr];
            bl[n] = *(const bf16x8*)&sBl[col * 32 + kgr];
        }
#pragma unroll
        for (int m = 0; m < 2; ++m)
#pragma unroll
            for (int n = 0; n < 4; ++n) {
                acc[m][n] = __builtin_amdgcn_mfma_f32_16x16x32_bf16(ah[m], bh[n], acc[m][n], 0, 0, 0);
                acc[m][n] = __builtin_amdgcn_mfma_f32_16x16x32_bf16(al[m], bh[n], acc[m][n], 0, 0, 0);
                acc[m][n] = __builtin_amdgcn_mfma_f32_16x16x32_bf16(ah[m], bl[n], acc[m][n], 0, 0, 0);
            }
    }

    // C/D layout (m89-verified): col = l&15, row = (l>>4)*4 + r
    const int rq = (l >> 4) * 4;
#pragma unroll
    for (int m = 0; m < 2; ++m) {
        int row = m0 + wr * 32 + m * 16 + rq;
#pragma unroll
        for (int n = 0; n < 4; ++n) {
            int col = n0 + wc * 64 + n * 16 + lr;
#pragma unroll
            for (int r = 0; r < 4; ++r)
                hh[(size_t)(row + r) * HID + col] = (bf16_t)acc[m][n][r];
        }
    }
}

// ---------------------------------------------------------------------------
// Aggregation: out[n] = relu( sum_{e->n} w_e * hh[src_e] + dinv[n]^2 * hh[n] + b )
// one wave per node, lane owns 8 contiguous cols (bf16x8 = 16B/lane per row)
// ---------------------------------------------------------------------------
template <bool LAST>
__global__ __launch_bounds__(256) void agg_k(
    const bf16_t* __restrict__ hh, const int* __restrict__ off,
    const int2* __restrict__ epk,
    const float* __restrict__ dinv, const float* __restrict__ bias,
    bf16_t* __restrict__ xh, bf16_t* __restrict__ xl, float* __restrict__ x3)
{
    int node = blockIdx.x * 4 + (threadIdx.x >> 6);
    if (node >= N_NODES) return;
    int l  = threadIdx.x & 63;
    int c0 = l * 8;

    float dn = dinv[node];
    float sw = dn * dn;
    float a[8];
    {
        bf16x8 sv = *(const bf16x8*)&hh[(size_t)node * HID + c0];
#pragma unroll
        for (int j = 0; j < 8; ++j) a[j] = (float)sv[j] * sw;
    }

    int e0 = off[node], e1 = off[node + 1];
    for (int e = e0; e < e1; ++e) {
        int2 ed = epk[e];
        float w = __int_as_float(ed.y);
        bf16x8 v = *(const bf16x8*)&hh[(size_t)ed.x * HID + c0];
#pragma unroll
        for (int j = 0; j < 8; ++j) a[j] += (float)v[j] * w;
    }
#pragma unroll
    for (int j = 0; j < 8; ++j) {
        a[j] += bias[c0 + j];
        if (a[j] < 0.f) a[j] = 0.f;
    }

    if (LAST) {
        f32x4 o0 = {a[0], a[1], a[2], a[3]};
        f32x4 o1 = {a[4], a[5], a[6], a[7]};
        *(f32x4*)&x3[(size_t)node * HID + c0]     = o0;
        *(f32x4*)&x3[(size_t)node * HID + c0 + 4] = o1;
    } else {
        bf16x8 hi, lo;
#pragma unroll
        for (int j = 0; j < 8; ++j) {
            bf16_t hb = (bf16_t)a[j];
            hi[j] = hb;
            lo[j] = (bf16_t)(a[j] - (float)hb);
        }
        *(bf16x8*)&xh[(size_t)node * HID + c0] = hi;
        *(bf16x8*)&xl[(size_t)node * HID + c0] = lo;
    }
}

// ---------------------------------------------------------------------------
// Pooling: pooled[g][c] += x3[n][c] for batch[n]==g (batch sorted, run-flush)
// 500 blocks x 20 nodes — enough TLP; one atomic per (run, col).
// ---------------------------------------------------------------------------
__global__ void pool_k(const float* __restrict__ x3, const int* __restrict__ batch,
                       float* __restrict__ pooled) {
    int t  = threadIdx.x;            // 256: cols t and t+256
    int n0 = blockIdx.x * 20;
    int nend = min(n0 + 20, N_NODES);
    float acc0 = 0.f, acc1 = 0.f;
    int cur = -1;
    for (int n = n0; n < nend; ++n) {
        int g = batch[n];
        if (g != cur) {
            if (cur >= 0) {
                atomicAdd(&pooled[cur * HID + t], acc0);
                atomicAdd(&pooled[cur * HID + t + 256], acc1);
            }
            cur = g; acc0 = 0.f; acc1 = 0.f;
        }
        acc0 += x3[(size_t)n * HID + t];
        acc1 += x3[(size_t)n * HID + t + 256];
    }
    if (cur >= 0) {
        atomicAdd(&pooled[cur * HID + t], acc0);
        atomicAdd(&pooled[cur * HID + t + 256], acc1);
    }
}

// ---------------------------------------------------------------------------
// Head: logits = pooled @ lin_w + lin_b ; log_softmax. One wave per graph.
// ---------------------------------------------------------------------------
__global__ __launch_bounds__(64) void head_k(const float* __restrict__ pooled,
                                             const float* __restrict__ lw,
                                             const float* __restrict__ lb,
                                             float* __restrict__ out) {
    int g = blockIdx.x, l = threadIdx.x;
    float lg[10];
#pragma unroll
    for (int c = 0; c < N_CLASSES; ++c) {
        float s = 0.f;
        for (int k = l; k < HID; k += 64) s += pooled[g * HID + k] * lw[k * N_CLASSES + c];
        for (int o2 = 32; o2 > 0; o2 >>= 1) s += __shfl_down(s, o2);
        lg[c] = s;
    }
    if (l == 0) {
        float mx = -1e30f;
#pragma unroll
        for (int c = 0; c < N_CLASSES; ++c) { lg[c] += lb[c]; mx = fmaxf(mx, lg[c]); }
        float se = 0.f;
#pragma unroll
        for (int c = 0; c < N_CLASSES; ++c) se += expf(lg[c] - mx);
        float lse = logf(se);
#pragma unroll
        for (int c = 0; c < N_CLASSES; ++c) out[g * N_CLASSES + c] = lg[c] - mx - lse;
    }
}

// ---------------------------------------------------------------------------
extern "C" void kernel_launch(void* const* d_in, const int* in_sizes, int n_in,
                              void* d_out, int out_size, void* d_ws, size_t ws_size,
                              hipStream_t stream) {
    const float* x     = (const float*)d_in[0];
    const int*   ei    = (const int*)d_in[1];
    const int*   batch = (const int*)d_in[2];
    const float* Ws    = (const float*)d_in[3];
    const float* bs    = (const float*)d_in[4];
    const float* lw    = (const float*)d_in[5];
    const float* lb    = (const float*)d_in[6];
    float*       out   = (float*)d_out;
    const int E = in_sizes[1] / 2;
    const int* erow = ei;       // edge_index[0] = source
    const int* ecol = ei + E;   // edge_index[1] = target (aggregation index)

    char* p = (char*)d_ws;
    auto take = [&](size_t bytes) {
        char* q = p;
        p += (bytes + 255) & ~(size_t)255;
        return q;
    };
    bf16_t* xh    = (bf16_t*)take((size_t)MPAD * HID * 2);
    bf16_t* xl    = (bf16_t*)take((size_t)MPAD * HID * 2);
    bf16_t* hh    = (bf16_t*)take((size_t)MPAD * HID * 2);
    float*  x3    = (float*) take((size_t)N_NODES * HID * 4);
    bf16_t* whT   = (bf16_t*)take((size_t)3 * HID * HID * 2);
    bf16_t* wlT   = (bf16_t*)take((size_t)3 * HID * HID * 2);
    float*  dinv  = (float*) take((size_t)N_NODES * 4);
    int*    cnt   = (int*)   take((size_t)N_NODES * 4);
    int*    off   = (int*)   take((size_t)(N_NODES + 1) * 4);
    int*    cur   = (int*)   take((size_t)N_NODES * 4);
    int2*   epk   = (int2*)  take((size_t)E * 8);
    float*  pooled= (float*) take((size_t)N_GRAPHS * HID * 4);

    zero_k<<<40, 256, 0, stream>>>(cnt, cur, xh + (size_t)N_NODES * HID,
                                   xl + (size_t)N_NODES * HID, pooled);
    conv_x<<<(N_NODES * HID) / (256 * 8), 256, 0, stream>>>(x, xh, xl);
    conv_w<<<(3 * HID * HID) / 256, 256, 0, stream>>>(Ws, whT, wlT);
    count_deg<<<(E + 255) / 256, 256, 0, stream>>>(ecol, cnt, E);
    scan_k<<<1, 1024, 0, stream>>>(cnt, off, dinv);
    scatter_k<<<(E + 255) / 256, 256, 0, stream>>>(erow, ecol, off, cur, dinv, epk, E);

    for (int lyr = 0; lyr < 3; ++lyr) {
        gemm3<<<dim3(4, 158), 256, 0, stream>>>(
            xh, xl, whT + (size_t)lyr * HID * HID, wlT + (size_t)lyr * HID * HID, hh);
        if (lyr < 2)
            agg_k<false><<<(N_NODES + 3) / 4, 256, 0, stream>>>(
                hh, off, epk, dinv, bs + lyr * HID, xh, xl, nullptr);
        else
            agg_k<true><<<(N_NODES + 3) / 4, 256, 0, stream>>>(
                hh, off, epk, dinv, bs + lyr * HID, nullptr, nullptr, x3);
    }
    pool_k<<<500, 256, 0, stream>>>(x3, batch, pooled);
    head_k<<<N_GRAPHS, 64, 0, stream>>>(pooled, lw, lb, out);
}

// Round 7
// 224.991 us; speedup vs baseline: 1.5112x; 1.0918x over previous
//
#include <hip/hip_runtime.h>

#define N_NODES 10000
#define HID 512
#define MPAD 10112          // 158 * 64
#define N_GRAPHS 64
#define N_CLASSES 10

typedef __bf16 bf16_t;
typedef __bf16 bf16x8 __attribute__((ext_vector_type(8)));
typedef float  f32x4  __attribute__((ext_vector_type(4)));

// ---------------------------------------------------------------------------
// async global->LDS 16B copy (gfx950). LDS dest is wave-uniform base + lane*16;
// our chunk->thread mapping is linear so per-lane dst pointers satisfy that.
// ---------------------------------------------------------------------------
__device__ __forceinline__ void gload16(const bf16_t* g, bf16_t* l) {
    __builtin_amdgcn_global_load_lds(
        (const __attribute__((address_space(1))) void*)g,
        (__attribute__((address_space(3))) void*)l,
        16, 0, 0);
}

// ---------------------------------------------------------------------------
// zero_k: cnt, cur, xh/xl pad rows, pooled — one dispatch replaces 5 memsets
// ---------------------------------------------------------------------------
__global__ void zero_k(int* __restrict__ cnt, int* __restrict__ cur,
                       bf16_t* __restrict__ xh_pad, bf16_t* __restrict__ xl_pad,
                       float* __restrict__ pooled) {
    int i = blockIdx.x * 256 + threadIdx.x;          // grid 40*256 = 10240
    if (i < N_NODES) { cnt[i] = 0; cur[i] = 0; }
    const int PCH = (MPAD - N_NODES) * HID / 8;      // 7168 16B-chunks
    uint4 z = {0, 0, 0, 0};
    if (i < PCH) {
        *(uint4*)&xh_pad[i * 8] = z;
        *(uint4*)&xl_pad[i * 8] = z;
    }
    if (i < N_GRAPHS * HID / 4) *(uint4*)&pooled[i * 4] = z;
}

// ---------------------------------------------------------------------------
// Input conversion: x (fp32) -> bf16 hi/lo pair (split-GEMM precision on A)
// ---------------------------------------------------------------------------
__global__ void conv_x(const float* __restrict__ x,
                       bf16_t* __restrict__ xh, bf16_t* __restrict__ xl) {
    int idx = (blockIdx.x * 256 + threadIdx.x) * 8;   // < N_NODES*HID
    f32x4 v0 = *(const f32x4*)&x[idx];
    f32x4 v1 = *(const f32x4*)&x[idx + 4];
    float v[8] = {v0[0], v0[1], v0[2], v0[3], v1[0], v1[1], v1[2], v1[3]};
    bf16x8 hi, lo;
#pragma unroll
    for (int j = 0; j < 8; ++j) {
        bf16_t h = (bf16_t)v[j];
        hi[j] = h;
        lo[j] = (bf16_t)(v[j] - (float)h);
    }
    *(bf16x8*)&xh[idx] = hi;
    *(bf16x8*)&xl[idx] = lo;
}

// W [3][512][512] row-major (W[l][k][j]) -> transposed bf16 (hi only): WT[l][j][k]
// (2-term split: W's low half dropped — adds ~0.2% rel err, same order as
//  the bf16 hh-table rounding already accepted)
__global__ void conv_w(const float* __restrict__ W,
                       bf16_t* __restrict__ whT) {
    int o   = blockIdx.x * 256 + threadIdx.x;  // < 3*512*512, output-indexed
    int lyr = o >> 18;
    int rem = o & 262143;
    int j   = rem >> 9;
    int k   = rem & 511;
    float v = W[(lyr << 18) + (k << 9) + j];
    whT[o] = (bf16_t)v;
}

// ---------------------------------------------------------------------------
// Degree + CSR build (grouped by target col), no fp32 atomics in hot path
// ---------------------------------------------------------------------------
__global__ void count_deg(const int* __restrict__ col, int* __restrict__ cnt, int E) {
    int e = blockIdx.x * 256 + threadIdx.x;
    if (e < E) atomicAdd(&cnt[col[e]], 1);
}

// scan (exclusive prefix over cnt -> off) + dinv fused (reads cnt anyway)
__global__ __launch_bounds__(1024) void scan_k(const int* __restrict__ cnt,
                                               int* __restrict__ off,
                                               float* __restrict__ dinv) {
    __shared__ int s[1024];
    int t = threadIdx.x;
    int base = t * 10;
    int loc[10];
    int sum = 0;
#pragma unroll
    for (int j = 0; j < 10; ++j) {
        int n = base + j;
        int v = (n < N_NODES) ? cnt[n] : 0;
        if (n < N_NODES) dinv[n] = rsqrtf(1.0f + (float)v);  // +1 self-loop
        loc[j] = sum;
        sum += v;
    }
    s[t] = sum;
    __syncthreads();
    for (int o = 1; o < 1024; o <<= 1) {
        int v = (t >= o) ? s[t - o] : 0;
        __syncthreads();
        s[t] += v;
        __syncthreads();
    }
    int pre = (t > 0) ? s[t - 1] : 0;
#pragma unroll
    for (int j = 0; j < 10; ++j) {
        int n = base + j;
        if (n <= N_NODES) off[n] = pre + loc[j];
    }
}

// packed edge record: .x = src index, .y = float bits of weight
__global__ void scatter_k(const int* __restrict__ row, const int* __restrict__ col,
                          const int* __restrict__ off, int* __restrict__ cursor,
                          const float* __restrict__ dinv,
                          int2* __restrict__ epk, int E) {
    int e = blockIdx.x * 256 + threadIdx.x;
    if (e >= E) return;
    int c = col[e], r = row[e];
    int p = off[c] + atomicAdd(&cursor[c], 1);
    float w = dinv[r] * dinv[c];
    epk[p] = make_int2(r, __float_as_int(w));
}

// ---------------------------------------------------------------------------
// GEMM: hh[MPAD][512] = bf16( (xh+xl) @ Wh )  via 2-term bf16 MFMA split
// 64x128 tile, 4 waves (2x2), 32x64/wave, BK=32, global_load_lds staging.
// 16 MFMA : 8 ds_read_b128 : 4 gload16 per wave-K-step; LDS 16 KB.
// ---------------------------------------------------------------------------
__global__ __launch_bounds__(256) void gemm3(
    const bf16_t* __restrict__ xh, const bf16_t* __restrict__ xl,
    const bf16_t* __restrict__ wh,   // [512][512] = W^T[j][k]
    bf16_t* __restrict__ hh)
{
    __shared__ alignas(16) bf16_t sAh[64 * 32];
    __shared__ alignas(16) bf16_t sAl[64 * 32];
    __shared__ alignas(16) bf16_t sBh[128 * 32];

    const int t  = threadIdx.x;
    const int l  = t & 63;
    const int wv = t >> 6;
    const int wr = wv >> 1;   // 0..1: 32-row half of M-tile
    const int wc = wv & 1;    // 0..1: 64-col half of N-tile
    const int n0 = blockIdx.x * 128;
    const int m0 = blockIdx.y * 64;

    f32x4 acc[2][4];
#pragma unroll
    for (int m = 0; m < 2; ++m)
#pragma unroll
        for (int n = 0; n < 4; ++n) acc[m][n] = (f32x4){0.f, 0.f, 0.f, 0.f};

    const int lr  = l & 15;
    const int kgr = (l >> 4) * 8;        // k-group start within BK=32
    const int srow = t >> 2;             // staging row 0..63
    const int sce  = (t & 3) * 8;        // staging element offset within row

    for (int kk = 0; kk < HID; kk += 32) {
        __syncthreads();  // previous iter's readers done before overwrite
        {
            size_t gA  = (size_t)(m0 + srow) * HID + kk + sce;
            size_t gB0 = (size_t)(n0 + srow) * HID + kk + sce;
            size_t gB1 = (size_t)(n0 + 64 + srow) * HID + kk + sce;
            gload16(&xh[gA],  &sAh[t * 8]);
            gload16(&xl[gA],  &sAl[t * 8]);
            gload16(&wh[gB0], &sBh[t * 8]);
            gload16(&wh[gB1], &sBh[(t + 256) * 8]);
        }
        __syncthreads();

        bf16x8 ah[2], al[2], bh[4];
#pragma unroll
        for (int m = 0; m < 2; ++m) {
            int row = wr * 32 + m * 16 + lr;
            ah[m] = *(const bf16x8*)&sAh[row * 32 + kgr];
            al[m] = *(const bf16x8*)&sAl[row * 32 + kgr];
        }
#pragma unroll
        for (int n = 0; n < 4; ++n) {
            int col = wc * 64 + n * 16 + lr;
            bh[n] = *(const bf16x8*)&sBh[col * 32 + kgr];
        }
#pragma unroll
        for (int m = 0; m < 2; ++m)
#pragma unroll
            for (int n = 0; n < 4; ++n) {
                acc[m][n] = __builtin_amdgcn_mfma_f32_16x16x32_bf16(ah[m], bh[n], acc[m][n], 0, 0, 0);
                acc[m][n] = __builtin_amdgcn_mfma_f32_16x16x32_bf16(al[m], bh[n], acc[m][n], 0, 0, 0);
            }
    }

    // C/D layout (m89-verified): col = l&15, row = (l>>4)*4 + r
    const int rq = (l >> 4) * 4;
#pragma unroll
    for (int m = 0; m < 2; ++m) {
        int row = m0 + wr * 32 + m * 16 + rq;
#pragma unroll
        for (int n = 0; n < 4; ++n) {
            int col = n0 + wc * 64 + n * 16 + lr;
#pragma unroll
            for (int r = 0; r < 4; ++r)
                hh[(size_t)(row + r) * HID + col] = (bf16_t)acc[m][n][r];
        }
    }
}

// ---------------------------------------------------------------------------
// Aggregation: out[n] = relu( sum_{e->n} w_e * hh[src_e] + dinv[n]^2 * hh[n] + b )
// one wave per node, lane owns 8 contiguous cols (bf16x8 = 16B/lane per row)
// ---------------------------------------------------------------------------
template <bool LAST>
__global__ __launch_bounds__(256) void agg_k(
    const bf16_t* __restrict__ hh, const int* __restrict__ off,
    const int2* __restrict__ epk,
    const float* __restrict__ dinv, const float* __restrict__ bias,
    bf16_t* __restrict__ xh, bf16_t* __restrict__ xl, float* __restrict__ x3)
{
    int node = blockIdx.x * 4 + (threadIdx.x >> 6);
    if (node >= N_NODES) return;
    int l  = threadIdx.x & 63;
    int c0 = l * 8;

    float dn = dinv[node];
    float sw = dn * dn;
    float a[8];
    {
        bf16x8 sv = *(const bf16x8*)&hh[(size_t)node * HID + c0];
#pragma unroll
        for (int j = 0; j < 8; ++j) a[j] = (float)sv[j] * sw;
    }

    int e0 = off[node], e1 = off[node + 1];
    for (int e = e0; e < e1; ++e) {
        int2 ed = epk[e];
        float w = __int_as_float(ed.y);
        bf16x8 v = *(const bf16x8*)&hh[(size_t)ed.x * HID + c0];
#pragma unroll
        for (int j = 0; j < 8; ++j) a[j] += (float)v[j] * w;
    }
#pragma unroll
    for (int j = 0; j < 8; ++j) {
        a[j] += bias[c0 + j];
        if (a[j] < 0.f) a[j] = 0.f;
    }

    if (LAST) {
        f32x4 o0 = {a[0], a[1], a[2], a[3]};
        f32x4 o1 = {a[4], a[5], a[6], a[7]};
        *(f32x4*)&x3[(size_t)node * HID + c0]     = o0;
        *(f32x4*)&x3[(size_t)node * HID + c0 + 4] = o1;
    } else {
        bf16x8 hi, lo;
#pragma unroll
        for (int j = 0; j < 8; ++j) {
            bf16_t hb = (bf16_t)a[j];
            hi[j] = hb;
            lo[j] = (bf16_t)(a[j] - (float)hb);
        }
        *(bf16x8*)&xh[(size_t)node * HID + c0] = hi;
        *(bf16x8*)&xl[(size_t)node * HID + c0] = lo;
    }
}

// ---------------------------------------------------------------------------
// Pooling: pooled[g][c] += x3[n][c] for batch[n]==g (batch sorted, run-flush)
// 500 blocks x 20 nodes — enough TLP; one atomic per (run, col).
// ---------------------------------------------------------------------------
__global__ void pool_k(const float* __restrict__ x3, const int* __restrict__ batch,
                       float* __restrict__ pooled) {
    int t  = threadIdx.x;            // 256: cols t and t+256
    int n0 = blockIdx.x * 20;
    int nend = min(n0 + 20, N_NODES);
    float acc0 = 0.f, acc1 = 0.f;
    int cur = -1;
    for (int n = n0; n < nend; ++n) {
        int g = batch[n];
        if (g != cur) {
            if (cur >= 0) {
                atomicAdd(&pooled[cur * HID + t], acc0);
                atomicAdd(&pooled[cur * HID + t + 256], acc1);
            }
            cur = g; acc0 = 0.f; acc1 = 0.f;
        }
        acc0 += x3[(size_t)n * HID + t];
        acc1 += x3[(size_t)n * HID + t + 256];
    }
    if (cur >= 0) {
        atomicAdd(&pooled[cur * HID + t], acc0);
        atomicAdd(&pooled[cur * HID + t + 256], acc1);
    }
}

// ---------------------------------------------------------------------------
// Head: logits = pooled @ lin_w + lin_b ; log_softmax. One wave per graph.
// ---------------------------------------------------------------------------
__global__ __launch_bounds__(64) void head_k(const float* __restrict__ pooled,
                                             const float* __restrict__ lw,
                                             const float* __restrict__ lb,
                                             float* __restrict__ out) {
    int g = blockIdx.x, l = threadIdx.x;
    float lg[10];
#pragma unroll
    for (int c = 0; c < N_CLASSES; ++c) {
        float s = 0.f;
        for (int k = l; k < HID; k += 64) s += pooled[g * HID + k] * lw[k * N_CLASSES + c];
        for (int o2 = 32; o2 > 0; o2 >>= 1) s += __shfl_down(s, o2);
        lg[c] = s;
    }
    if (l == 0) {
        float mx = -1e30f;
#pragma unroll
        for (int c = 0; c < N_CLASSES; ++c) { lg[c] += lb[c]; mx = fmaxf(mx, lg[c]); }
        float se = 0.f;
#pragma unroll
        for (int c = 0; c < N_CLASSES; ++c) se += expf(lg[c] - mx);
        float lse = logf(se);
#pragma unroll
        for (int c = 0; c < N_CLASSES; ++c) out[g * N_CLASSES + c] = lg[c] - mx - lse;
    }
}

// ---------------------------------------------------------------------------
extern "C" void kernel_launch(void* const* d_in, const int* in_sizes, int n_in,
                              void* d_out, int out_size, void* d_ws, size_t ws_size,
                              hipStream_t stream) {
    const float* x     = (const float*)d_in[0];
    const int*   ei    = (const int*)d_in[1];
    const int*   batch = (const int*)d_in[2];
    const float* Ws    = (const float*)d_in[3];
    const float* bs    = (const float*)d_in[4];
    const float* lw    = (const float*)d_in[5];
    const float* lb    = (const float*)d_in[6];
    float*       out   = (float*)d_out;
    const int E = in_sizes[1] / 2;
    const int* erow = ei;       // edge_index[0] = source
    const int* ecol = ei + E;   // edge_index[1] = target (aggregation index)

    char* p = (char*)d_ws;
    auto take = [&](size_t bytes) {
        char* q = p;
        p += (bytes + 255) & ~(size_t)255;
        return q;
    };
    bf16_t* xh    = (bf16_t*)take((size_t)MPAD * HID * 2);
    bf16_t* xl    = (bf16_t*)take((size_t)MPAD * HID * 2);
    bf16_t* hh    = (bf16_t*)take((size_t)MPAD * HID * 2);
    float*  x3    = (float*) take((size_t)N_NODES * HID * 4);
    bf16_t* whT   = (bf16_t*)take((size_t)3 * HID * HID * 2);
    float*  dinv  = (float*) take((size_t)N_NODES * 4);
    int*    cnt   = (int*)   take((size_t)N_NODES * 4);
    int*    off   = (int*)   take((size_t)(N_NODES + 1) * 4);
    int*    cur   = (int*)   take((size_t)N_NODES * 4);
    int2*   epk   = (int2*)  take((size_t)E * 8);
    float*  pooled= (float*) take((size_t)N_GRAPHS * HID * 4);

    zero_k<<<40, 256, 0, stream>>>(cnt, cur, xh + (size_t)N_NODES * HID,
                                   xl + (size_t)N_NODES * HID, pooled);
    conv_x<<<(N_NODES * HID) / (256 * 8), 256, 0, stream>>>(x, xh, xl);
    conv_w<<<(3 * HID * HID) / 256, 256, 0, stream>>>(Ws, whT);
    count_deg<<<(E + 255) / 256, 256, 0, stream>>>(ecol, cnt, E);
    scan_k<<<1, 1024, 0, stream>>>(cnt, off, dinv);
    scatter_k<<<(E + 255) / 256, 256, 0, stream>>>(erow, ecol, off, cur, dinv, epk, E);

    for (int lyr = 0; lyr < 3; ++lyr) {
        gemm3<<<dim3(4, 158), 256, 0, stream>>>(
            xh, xl, whT + (size_t)lyr * HID * HID, hh);
        if (lyr < 2)
            agg_k<false><<<(N_NODES + 3) / 4, 256, 0, stream>>>(
                hh, off, epk, dinv, bs + lyr * HID, xh, xl, nullptr);
        else
            agg_k<true><<<(N_NODES + 3) / 4, 256, 0, stream>>>(
                hh, off, epk, dinv, bs + lyr * HID, nullptr, nullptr, x3);
    }
    pool_k<<<500, 256, 0, stream>>>(x3, batch, pooled);
    head_k<<<N_GRAPHS, 64, 0, stream>>>(pooled, lw, lb, out);
}

// Round 8
// 218.358 us; speedup vs baseline: 1.5571x; 1.0304x over previous
//
#include <hip/hip_runtime.h>

#define N_NODES 10000
#define HID 512
#define MPAD 10112          // 158 * 64
#define N_GRAPHS 64
#define N_CLASSES 10

typedef __bf16 bf16_t;
typedef __bf16 bf16x8 __attribute__((ext_vector_type(8)));
typedef float  f32x4  __attribute__((ext_vector_type(4)));

// ---------------------------------------------------------------------------
// async global->LDS 16B copy (gfx950). LDS dest is wave-uniform base + lane*16;
// our chunk->thread mapping is linear so per-lane dst pointers satisfy that.
// ---------------------------------------------------------------------------
__device__ __forceinline__ void gload16(const bf16_t* g, bf16_t* l) {
    __builtin_amdgcn_global_load_lds(
        (const __attribute__((address_space(1))) void*)g,
        (__attribute__((address_space(3))) void*)l,
        16, 0, 0);
}

// ---------------------------------------------------------------------------
// zero_k: cnt, cur, xh/xl pad rows, pooled — one dispatch replaces 5 memsets
// ---------------------------------------------------------------------------
__global__ void zero_k(int* __restrict__ cnt, int* __restrict__ cur,
                       bf16_t* __restrict__ xh_pad, bf16_t* __restrict__ xl_pad,
                       float* __restrict__ pooled) {
    int i = blockIdx.x * 256 + threadIdx.x;          // grid 40*256 = 10240
    if (i < N_NODES) { cnt[i] = 0; cur[i] = 0; }
    const int PCH = (MPAD - N_NODES) * HID / 8;      // 7168 16B-chunks
    uint4 z = {0, 0, 0, 0};
    if (i < PCH) {
        *(uint4*)&xh_pad[i * 8] = z;
        *(uint4*)&xl_pad[i * 8] = z;
    }
    if (i < N_GRAPHS * HID / 4) *(uint4*)&pooled[i * 4] = z;
}

// ---------------------------------------------------------------------------
// setup_k: conv_x (blocks 0..2499) + conv_w (2500..5571) + count_deg (5572..)
// three independent range-dispatched phases fused into one launch.
// ---------------------------------------------------------------------------
#define CVX_B 2500
#define CVW_B 3072
__global__ void setup_k(const float* __restrict__ x,
                        bf16_t* __restrict__ xh, bf16_t* __restrict__ xl,
                        const float* __restrict__ W, bf16_t* __restrict__ whT,
                        const int* __restrict__ ecol, int* __restrict__ cnt, int E) {
    int b = blockIdx.x, t = threadIdx.x;
    if (b < CVX_B) {
        // x (fp32) -> bf16 hi/lo pair (split-GEMM precision on A)
        int idx = (b * 256 + t) * 8;                 // < N_NODES*HID
        f32x4 v0 = *(const f32x4*)&x[idx];
        f32x4 v1 = *(const f32x4*)&x[idx + 4];
        float v[8] = {v0[0], v0[1], v0[2], v0[3], v1[0], v1[1], v1[2], v1[3]};
        bf16x8 hi, lo;
#pragma unroll
        for (int j = 0; j < 8; ++j) {
            bf16_t h = (bf16_t)v[j];
            hi[j] = h;
            lo[j] = (bf16_t)(v[j] - (float)h);
        }
        *(bf16x8*)&xh[idx] = hi;
        *(bf16x8*)&xl[idx] = lo;
    } else if (b < CVX_B + CVW_B) {
        // W [3][512][512] (W[l][k][j]) -> transposed bf16 hi: WT[l][j][k]
        int o   = (b - CVX_B) * 256 + t;             // < 3*512*512
        int lyr = o >> 18;
        int rem = o & 262143;
        int j   = rem >> 9;
        int k   = rem & 511;
        whT[o] = (bf16_t)W[(lyr << 18) + (k << 9) + j];
    } else {
        int e = (b - CVX_B - CVW_B) * 256 + t;
        if (e < E) atomicAdd(&cnt[ecol[e]], 1);
    }
}

// scan (exclusive prefix over cnt -> off) + dinv fused (reads cnt anyway)
__global__ __launch_bounds__(1024) void scan_k(const int* __restrict__ cnt,
                                               int* __restrict__ off,
                                               float* __restrict__ dinv) {
    __shared__ int s[1024];
    int t = threadIdx.x;
    int base = t * 10;
    int loc[10];
    int sum = 0;
#pragma unroll
    for (int j = 0; j < 10; ++j) {
        int n = base + j;
        int v = (n < N_NODES) ? cnt[n] : 0;
        if (n < N_NODES) dinv[n] = rsqrtf(1.0f + (float)v);  // +1 self-loop
        loc[j] = sum;
        sum += v;
    }
    s[t] = sum;
    __syncthreads();
    for (int o = 1; o < 1024; o <<= 1) {
        int v = (t >= o) ? s[t - o] : 0;
        __syncthreads();
        s[t] += v;
        __syncthreads();
    }
    int pre = (t > 0) ? s[t - 1] : 0;
#pragma unroll
    for (int j = 0; j < 10; ++j) {
        int n = base + j;
        if (n <= N_NODES) off[n] = pre + loc[j];
    }
}

// packed edge record: .x = src index, .y = float bits of weight
__global__ void scatter_k(const int* __restrict__ row, const int* __restrict__ col,
                          const int* __restrict__ off, int* __restrict__ cursor,
                          const float* __restrict__ dinv,
                          int2* __restrict__ epk, int E) {
    int e = blockIdx.x * 256 + threadIdx.x;
    if (e >= E) return;
    int c = col[e], r = row[e];
    int p = off[c] + atomicAdd(&cursor[c], 1);
    float w = dinv[r] * dinv[c];
    epk[p] = make_int2(r, __float_as_int(w));
}

// ---------------------------------------------------------------------------
// GEMM: hh[MPAD][512] = bf16( (xh+xl) @ Wh )  via 2-term bf16 MFMA split
// 64x128 tile, 4 waves (2x2), 32x64/wave, BK=32, global_load_lds staging,
// DOUBLE-BUFFERED 2-phase: stage(next) || compute(cur), ONE barrier/iter.
// Load latency hides under the ds_read+MFMA phase (T3-lite, m230 pattern).
// ---------------------------------------------------------------------------
__global__ __launch_bounds__(256) void gemm3(
    const bf16_t* __restrict__ xh, const bf16_t* __restrict__ xl,
    const bf16_t* __restrict__ wh,   // [512][512] = W^T[j][k]
    bf16_t* __restrict__ hh)
{
    __shared__ alignas(16) bf16_t sAh[2][64 * 32];
    __shared__ alignas(16) bf16_t sAl[2][64 * 32];
    __shared__ alignas(16) bf16_t sBh[2][128 * 32];

    const int t  = threadIdx.x;
    const int l  = t & 63;
    const int wv = t >> 6;
    const int wr = wv >> 1;   // 0..1: 32-row half of M-tile
    const int wc = wv & 1;    // 0..1: 64-col half of N-tile
    const int n0 = blockIdx.x * 128;
    const int m0 = blockIdx.y * 64;

    f32x4 acc[2][4];
#pragma unroll
    for (int m = 0; m < 2; ++m)
#pragma unroll
        for (int n = 0; n < 4; ++n) acc[m][n] = (f32x4){0.f, 0.f, 0.f, 0.f};

    const int lr  = l & 15;
    const int kgr = (l >> 4) * 8;        // k-group start within BK=32
    const int srow = t >> 2;             // staging row 0..63
    const int sce  = (t & 3) * 8;        // staging element offset within row

    auto stage = [&](int buf, int kk) {
        size_t gA  = (size_t)(m0 + srow) * HID + kk + sce;
        size_t gB0 = (size_t)(n0 + srow) * HID + kk + sce;
        size_t gB1 = (size_t)(n0 + 64 + srow) * HID + kk + sce;
        gload16(&xh[gA],  &sAh[buf][t * 8]);
        gload16(&xl[gA],  &sAl[buf][t * 8]);
        gload16(&wh[gB0], &sBh[buf][t * 8]);
        gload16(&wh[gB1], &sBh[buf][(t + 256) * 8]);
    };

    stage(0, 0);
    __syncthreads();           // drains vmcnt(0): buf0 ready

    int cur = 0;
    for (int kk = 0; kk < HID; kk += 32) {
        if (kk + 32 < HID) stage(cur ^ 1, kk + 32);   // issue next-tile loads

        bf16x8 ah[2], al[2], bh[4];
#pragma unroll
        for (int m = 0; m < 2; ++m) {
            int row = wr * 32 + m * 16 + lr;
            ah[m] = *(const bf16x8*)&sAh[cur][row * 32 + kgr];
            al[m] = *(const bf16x8*)&sAl[cur][row * 32 + kgr];
        }
#pragma unroll
        for (int n = 0; n < 4; ++n) {
            int col = wc * 64 + n * 16 + lr;
            bh[n] = *(const bf16x8*)&sBh[cur][col * 32 + kgr];
        }
#pragma unroll
        for (int m = 0; m < 2; ++m)
#pragma unroll
            for (int n = 0; n < 4; ++n) {
                acc[m][n] = __builtin_amdgcn_mfma_f32_16x16x32_bf16(ah[m], bh[n], acc[m][n], 0, 0, 0);
                acc[m][n] = __builtin_amdgcn_mfma_f32_16x16x32_bf16(al[m], bh[n], acc[m][n], 0, 0, 0);
            }

        __syncthreads();       // drains vmcnt(0) (next buf written) + lgkm
        cur ^= 1;
    }

    // C/D layout (m89-verified): col = l&15, row = (l>>4)*4 + r
    const int rq = (l >> 4) * 4;
#pragma unroll
    for (int m = 0; m < 2; ++m) {
        int row = m0 + wr * 32 + m * 16 + rq;
#pragma unroll
        for (int n = 0; n < 4; ++n) {
            int col = n0 + wc * 64 + n * 16 + lr;
#pragma unroll
            for (int r = 0; r < 4; ++r)
                hh[(size_t)(row + r) * HID + col] = (bf16_t)acc[m][n][r];
        }
    }
}

// ---------------------------------------------------------------------------
// Aggregation: out[n] = relu( sum_{e->n} w_e * hh[src_e] + dinv[n]^2 * hh[n] + b )
// one wave per node, lane owns 8 contiguous cols (bf16x8 = 16B/lane per row)
// ---------------------------------------------------------------------------
template <bool LAST>
__global__ __launch_bounds__(256) void agg_k(
    const bf16_t* __restrict__ hh, const int* __restrict__ off,
    const int2* __restrict__ epk,
    const float* __restrict__ dinv, const float* __restrict__ bias,
    bf16_t* __restrict__ xh, bf16_t* __restrict__ xl, float* __restrict__ x3)
{
    int node = blockIdx.x * 4 + (threadIdx.x >> 6);
    if (node >= N_NODES) return;
    int l  = threadIdx.x & 63;
    int c0 = l * 8;

    float dn = dinv[node];
    float sw = dn * dn;
    float a[8];
    {
        bf16x8 sv = *(const bf16x8*)&hh[(size_t)node * HID + c0];
#pragma unroll
        for (int j = 0; j < 8; ++j) a[j] = (float)sv[j] * sw;
    }

    int e0 = off[node], e1 = off[node + 1];
    for (int e = e0; e < e1; ++e) {
        int2 ed = epk[e];
        float w = __int_as_float(ed.y);
        bf16x8 v = *(const bf16x8*)&hh[(size_t)ed.x * HID + c0];
#pragma unroll
        for (int j = 0; j < 8; ++j) a[j] += (float)v[j] * w;
    }
#pragma unroll
    for (int j = 0; j < 8; ++j) {
        a[j] += bias[c0 + j];
        if (a[j] < 0.f) a[j] = 0.f;
    }

    if (LAST) {
        f32x4 o0 = {a[0], a[1], a[2], a[3]};
        f32x4 o1 = {a[4], a[5], a[6], a[7]};
        *(f32x4*)&x3[(size_t)node * HID + c0]     = o0;
        *(f32x4*)&x3[(size_t)node * HID + c0 + 4] = o1;
    } else {
        bf16x8 hi, lo;
#pragma unroll
        for (int j = 0; j < 8; ++j) {
            bf16_t hb = (bf16_t)a[j];
            hi[j] = hb;
            lo[j] = (bf16_t)(a[j] - (float)hb);
        }
        *(bf16x8*)&xh[(size_t)node * HID + c0] = hi;
        *(bf16x8*)&xl[(size_t)node * HID + c0] = lo;
    }
}

// ---------------------------------------------------------------------------
// Pooling: pooled[g][c] += x3[n][c] for batch[n]==g (batch sorted, run-flush)
// 500 blocks x 20 nodes — enough TLP; one atomic per (run, col).
// ---------------------------------------------------------------------------
__global__ void pool_k(const float* __restrict__ x3, const int* __restrict__ batch,
                       float* __restrict__ pooled) {
    int t  = threadIdx.x;            // 256: cols t and t+256
    int n0 = blockIdx.x * 20;
    int nend = min(n0 + 20, N_NODES);
    float acc0 = 0.f, acc1 = 0.f;
    int cur = -1;
    for (int n = n0; n < nend; ++n) {
        int g = batch[n];
        if (g != cur) {
            if (cur >= 0) {
                atomicAdd(&pooled[cur * HID + t], acc0);
                atomicAdd(&pooled[cur * HID + t + 256], acc1);
            }
            cur = g; acc0 = 0.f; acc1 = 0.f;
        }
        acc0 += x3[(size_t)n * HID + t];
        acc1 += x3[(size_t)n * HID + t + 256];
    }
    if (cur >= 0) {
        atomicAdd(&pooled[cur * HID + t], acc0);
        atomicAdd(&pooled[cur * HID + t + 256], acc1);
    }
}

// ---------------------------------------------------------------------------
// Head: logits = pooled @ lin_w + lin_b ; log_softmax. One wave per graph.
// ---------------------------------------------------------------------------
__global__ __launch_bounds__(64) void head_k(const float* __restrict__ pooled,
                                             const float* __restrict__ lw,
                                             const float* __restrict__ lb,
                                             float* __restrict__ out) {
    int g = blockIdx.x, l = threadIdx.x;
    float lg[10];
#pragma unroll
    for (int c = 0; c < N_CLASSES; ++c) {
        float s = 0.f;
        for (int k = l; k < HID; k += 64) s += pooled[g * HID + k] * lw[k * N_CLASSES + c];
        for (int o2 = 32; o2 > 0; o2 >>= 1) s += __shfl_down(s, o2);
        lg[c] = s;
    }
    if (l == 0) {
        float mx = -1e30f;
#pragma unroll
        for (int c = 0; c < N_CLASSES; ++c) { lg[c] += lb[c]; mx = fmaxf(mx, lg[c]); }
        float se = 0.f;
#pragma unroll
        for (int c = 0; c < N_CLASSES; ++c) se += expf(lg[c] - mx);
        float lse = logf(se);
#pragma unroll
        for (int c = 0; c < N_CLASSES; ++c) out[g * N_CLASSES + c] = lg[c] - mx - lse;
    }
}

// ---------------------------------------------------------------------------
extern "C" void kernel_launch(void* const* d_in, const int* in_sizes, int n_in,
                              void* d_out, int out_size, void* d_ws, size_t ws_size,
                              hipStream_t stream) {
    const float* x     = (const float*)d_in[0];
    const int*   ei    = (const int*)d_in[1];
    const int*   batch = (const int*)d_in[2];
    const float* Ws    = (const float*)d_in[3];
    const float* bs    = (const float*)d_in[4];
    const float* lw    = (const float*)d_in[5];
    const float* lb    = (const float*)d_in[6];
    float*       out   = (float*)d_out;
    const int E = in_sizes[1] / 2;
    const int* erow = ei;       // edge_index[0] = source
    const int* ecol = ei + E;   // edge_index[1] = target (aggregation index)

    char* p = (char*)d_ws;
    auto take = [&](size_t bytes) {
        char* q = p;
        p += (bytes + 255) & ~(size_t)255;
        return q;
    };
    bf16_t* xh    = (bf16_t*)take((size_t)MPAD * HID * 2);
    bf16_t* xl    = (bf16_t*)take((size_t)MPAD * HID * 2);
    bf16_t* hh    = (bf16_t*)take((size_t)MPAD * HID * 2);
    float*  x3    = (float*) take((size_t)N_NODES * HID * 4);
    bf16_t* whT   = (bf16_t*)take((size_t)3 * HID * HID * 2);
    float*  dinv  = (float*) take((size_t)N_NODES * 4);
    int*    cnt   = (int*)   take((size_t)N_NODES * 4);
    int*    off   = (int*)   take((size_t)(N_NODES + 1) * 4);
    int*    cur   = (int*)   take((size_t)N_NODES * 4);
    int2*   epk   = (int2*)  take((size_t)E * 8);
    float*  pooled= (float*) take((size_t)N_GRAPHS * HID * 4);

    const int cdeg_b = (E + 255) / 256;
    zero_k<<<40, 256, 0, stream>>>(cnt, cur, xh + (size_t)N_NODES * HID,
                                   xl + (size_t)N_NODES * HID, pooled);
    setup_k<<<CVX_B + CVW_B + cdeg_b, 256, 0, stream>>>(
        x, xh, xl, Ws, whT, ecol, cnt, E);
    scan_k<<<1, 1024, 0, stream>>>(cnt, off, dinv);
    scatter_k<<<cdeg_b, 256, 0, stream>>>(erow, ecol, off, cur, dinv, epk, E);

    for (int lyr = 0; lyr < 3; ++lyr) {
        gemm3<<<dim3(4, 158), 256, 0, stream>>>(
            xh, xl, whT + (size_t)lyr * HID * HID, hh);
        if (lyr < 2)
            agg_k<false><<<(N_NODES + 3) / 4, 256, 0, stream>>>(
                hh, off, epk, dinv, bs + lyr * HID, xh, xl, nullptr);
        else
            agg_k<true><<<(N_NODES + 3) / 4, 256, 0, stream>>>(
                hh, off, epk, dinv, bs + lyr * HID, nullptr, nullptr, x3);
    }
    pool_k<<<500, 256, 0, stream>>>(x3, batch, pooled);
    head_k<<<N_GRAPHS, 64, 0, stream>>>(pooled, lw, lb, out);
}

// Round 9
// 195.798 us; speedup vs baseline: 1.7365x; 1.1152x over previous
//
#include <hip/hip_runtime.h>

#define N_NODES 10000
#define HID 512
#define MPAD 10112          // 158 * 64
#define N_GRAPHS 64
#define N_CLASSES 10

typedef __bf16 bf16_t;
typedef __bf16 bf16x8 __attribute__((ext_vector_type(8)));
typedef float  f32x4  __attribute__((ext_vector_type(4)));

// ---------------------------------------------------------------------------
// async global->LDS 16B copy (gfx950). LDS dest is wave-uniform base + lane*16;
// our chunk->thread mapping is linear so per-lane dst pointers satisfy that.
// ---------------------------------------------------------------------------
__device__ __forceinline__ void gload16(const bf16_t* g, bf16_t* l) {
    __builtin_amdgcn_global_load_lds(
        (const __attribute__((address_space(1))) void*)g,
        (__attribute__((address_space(3))) void*)l,
        16, 0, 0);
}

// ---------------------------------------------------------------------------
// zero_k: cnt, cur, xh/xl pad rows, pooled — one dispatch replaces 5 memsets
// ---------------------------------------------------------------------------
__global__ void zero_k(int* __restrict__ cnt, int* __restrict__ cur,
                       bf16_t* __restrict__ xh_pad, bf16_t* __restrict__ xl_pad,
                       float* __restrict__ pooled) {
    int i = blockIdx.x * 256 + threadIdx.x;          // grid 40*256 = 10240
    if (i < N_NODES) { cnt[i] = 0; cur[i] = 0; }
    const int PCH = (MPAD - N_NODES) * HID / 8;      // 7168 16B-chunks
    uint4 z = {0, 0, 0, 0};
    if (i < PCH) {
        *(uint4*)&xh_pad[i * 8] = z;
        *(uint4*)&xl_pad[i * 8] = z;
    }
    if (i < N_GRAPHS * HID / 4) *(uint4*)&pooled[i * 4] = z;
}

// ---------------------------------------------------------------------------
// setup_k: conv_x (blocks 0..2499) + conv_w (2500..5571) + count_deg (5572..)
// ---------------------------------------------------------------------------
#define CVX_B 2500
#define CVW_B 3072
__global__ void setup_k(const float* __restrict__ x,
                        bf16_t* __restrict__ xh, bf16_t* __restrict__ xl,
                        const float* __restrict__ W, bf16_t* __restrict__ whT,
                        const int* __restrict__ ecol, int* __restrict__ cnt, int E) {
    int b = blockIdx.x, t = threadIdx.x;
    if (b < CVX_B) {
        // x (fp32) -> bf16 hi/lo pair (split-GEMM precision on A)
        int idx = (b * 256 + t) * 8;                 // < N_NODES*HID
        f32x4 v0 = *(const f32x4*)&x[idx];
        f32x4 v1 = *(const f32x4*)&x[idx + 4];
        float v[8] = {v0[0], v0[1], v0[2], v0[3], v1[0], v1[1], v1[2], v1[3]};
        bf16x8 hi, lo;
#pragma unroll
        for (int j = 0; j < 8; ++j) {
            bf16_t h = (bf16_t)v[j];
            hi[j] = h;
            lo[j] = (bf16_t)(v[j] - (float)h);
        }
        *(bf16x8*)&xh[idx] = hi;
        *(bf16x8*)&xl[idx] = lo;
    } else if (b < CVX_B + CVW_B) {
        // W [3][512][512] (W[l][k][j]) -> transposed bf16 hi: WT[l][j][k]
        int o   = (b - CVX_B) * 256 + t;             // < 3*512*512
        int lyr = o >> 18;
        int rem = o & 262143;
        int j   = rem >> 9;
        int k   = rem & 511;
        whT[o] = (bf16_t)W[(lyr << 18) + (k << 9) + j];
    } else {
        int e = (b - CVX_B - CVW_B) * 256 + t;
        if (e < E) atomicAdd(&cnt[ecol[e]], 1);
    }
}

// scan (exclusive prefix over cnt -> off) + dinv fused (reads cnt anyway)
__global__ __launch_bounds__(1024) void scan_k(const int* __restrict__ cnt,
                                               int* __restrict__ off,
                                               float* __restrict__ dinv) {
    __shared__ int s[1024];
    int t = threadIdx.x;
    int base = t * 10;
    int loc[10];
    int sum = 0;
#pragma unroll
    for (int j = 0; j < 10; ++j) {
        int n = base + j;
        int v = (n < N_NODES) ? cnt[n] : 0;
        if (n < N_NODES) dinv[n] = rsqrtf(1.0f + (float)v);  // +1 self-loop
        loc[j] = sum;
        sum += v;
    }
    s[t] = sum;
    __syncthreads();
    for (int o = 1; o < 1024; o <<= 1) {
        int v = (t >= o) ? s[t - o] : 0;
        __syncthreads();
        s[t] += v;
        __syncthreads();
    }
    int pre = (t > 0) ? s[t - 1] : 0;
#pragma unroll
    for (int j = 0; j < 10; ++j) {
        int n = base + j;
        if (n <= N_NODES) off[n] = pre + loc[j];
    }
}

// packed edge record: .x = src index, .y = float bits of weight
__global__ void scatter_k(const int* __restrict__ row, const int* __restrict__ col,
                          const int* __restrict__ off, int* __restrict__ cursor,
                          const float* __restrict__ dinv,
                          int2* __restrict__ epk, int E) {
    int e = blockIdx.x * 256 + threadIdx.x;
    if (e >= E) return;
    int c = col[e], r = row[e];
    int p = off[c] + atomicAdd(&cursor[c], 1);
    float w = dinv[r] * dinv[c];
    epk[p] = make_int2(r, __float_as_int(w));
}

// ---------------------------------------------------------------------------
// GEMM: hh[MPAD][512] = bf16( (xh+xl) @ Wh )  via 2-term bf16 MFMA split
// 64x128 tile, 4 waves (2x2), 32x64/wave, BK=32, global_load_lds staging,
// double-buffered (control — unchanged this round)
// ---------------------------------------------------------------------------
__global__ __launch_bounds__(256) void gemm3(
    const bf16_t* __restrict__ xh, const bf16_t* __restrict__ xl,
    const bf16_t* __restrict__ wh,   // [512][512] = W^T[j][k]
    bf16_t* __restrict__ hh)
{
    __shared__ alignas(16) bf16_t sAh[2][64 * 32];
    __shared__ alignas(16) bf16_t sAl[2][64 * 32];
    __shared__ alignas(16) bf16_t sBh[2][128 * 32];

    const int t  = threadIdx.x;
    const int l  = t & 63;
    const int wv = t >> 6;
    const int wr = wv >> 1;   // 0..1: 32-row half of M-tile
    const int wc = wv & 1;    // 0..1: 64-col half of N-tile
    const int n0 = blockIdx.x * 128;
    const int m0 = blockIdx.y * 64;

    f32x4 acc[2][4];
#pragma unroll
    for (int m = 0; m < 2; ++m)
#pragma unroll
        for (int n = 0; n < 4; ++n) acc[m][n] = (f32x4){0.f, 0.f, 0.f, 0.f};

    const int lr  = l & 15;
    const int kgr = (l >> 4) * 8;        // k-group start within BK=32
    const int srow = t >> 2;             // staging row 0..63
    const int sce  = (t & 3) * 8;        // staging element offset within row

    auto stage = [&](int buf, int kk) {
        size_t gA  = (size_t)(m0 + srow) * HID + kk + sce;
        size_t gB0 = (size_t)(n0 + srow) * HID + kk + sce;
        size_t gB1 = (size_t)(n0 + 64 + srow) * HID + kk + sce;
        gload16(&xh[gA],  &sAh[buf][t * 8]);
        gload16(&xl[gA],  &sAl[buf][t * 8]);
        gload16(&wh[gB0], &sBh[buf][t * 8]);
        gload16(&wh[gB1], &sBh[buf][(t + 256) * 8]);
    };

    stage(0, 0);
    __syncthreads();           // drains vmcnt(0): buf0 ready

    int cur = 0;
    for (int kk = 0; kk < HID; kk += 32) {
        if (kk + 32 < HID) stage(cur ^ 1, kk + 32);   // issue next-tile loads

        bf16x8 ah[2], al[2], bh[4];
#pragma unroll
        for (int m = 0; m < 2; ++m) {
            int row = wr * 32 + m * 16 + lr;
            ah[m] = *(const bf16x8*)&sAh[cur][row * 32 + kgr];
            al[m] = *(const bf16x8*)&sAl[cur][row * 32 + kgr];
        }
#pragma unroll
        for (int n = 0; n < 4; ++n) {
            int col = wc * 64 + n * 16 + lr;
            bh[n] = *(const bf16x8*)&sBh[cur][col * 32 + kgr];
        }
#pragma unroll
        for (int m = 0; m < 2; ++m)
#pragma unroll
            for (int n = 0; n < 4; ++n) {
                acc[m][n] = __builtin_amdgcn_mfma_f32_16x16x32_bf16(ah[m], bh[n], acc[m][n], 0, 0, 0);
                acc[m][n] = __builtin_amdgcn_mfma_f32_16x16x32_bf16(al[m], bh[n], acc[m][n], 0, 0, 0);
            }

        __syncthreads();
        cur ^= 1;
    }

    // C/D layout (m89-verified): col = l&15, row = (l>>4)*4 + r
    const int rq = (l >> 4) * 4;
#pragma unroll
    for (int m = 0; m < 2; ++m) {
        int row = m0 + wr * 32 + m * 16 + rq;
#pragma unroll
        for (int n = 0; n < 4; ++n) {
            int col = n0 + wc * 64 + n * 16 + lr;
#pragma unroll
            for (int r = 0; r < 4; ++r)
                hh[(size_t)(row + r) * HID + col] = (bf16_t)acc[m][n][r];
        }
    }
}

// ---------------------------------------------------------------------------
// Aggregation: out[n] = relu( sum_{e->n} w_e * hh[src_e] + dinv[n]^2 * hh[n] + b )
// one wave per node, lane owns 8 contiguous cols. 4x-unrolled edge loop:
// batch 4 edge records (2x int4) + 4 independent row loads -> 4x MLP
// (round-2 counters: VALUBusy 7%, 53% occ, 3.25 TB/s = latency-bound)
// ---------------------------------------------------------------------------
template <bool LAST>
__global__ __launch_bounds__(256) void agg_k(
    const bf16_t* __restrict__ hh, const int* __restrict__ off,
    const int2* __restrict__ epk,
    const float* __restrict__ dinv, const float* __restrict__ bias,
    bf16_t* __restrict__ xh, bf16_t* __restrict__ xl, float* __restrict__ x3)
{
    int node = blockIdx.x * 4 + (threadIdx.x >> 6);
    if (node >= N_NODES) return;
    int l  = threadIdx.x & 63;
    int c0 = l * 8;

    float dn = dinv[node];
    float sw = dn * dn;
    float a[8];
    {
        bf16x8 sv = *(const bf16x8*)&hh[(size_t)node * HID + c0];
#pragma unroll
        for (int j = 0; j < 8; ++j) a[j] = (float)sv[j] * sw;
    }

    int e0 = off[node], e1 = off[node + 1];
    int e = e0;
    for (; e + 4 <= e1; e += 4) {
        // batch-load 4 edge records (independent of row loads)
        int4 p0 = *(const int4*)&epk[e];        // edges e, e+1
        int4 p1 = *(const int4*)&epk[e + 2];    // edges e+2, e+3
        // issue 4 independent row loads
        bf16x8 v0 = *(const bf16x8*)&hh[(size_t)p0.x * HID + c0];
        bf16x8 v1 = *(const bf16x8*)&hh[(size_t)p0.z * HID + c0];
        bf16x8 v2 = *(const bf16x8*)&hh[(size_t)p1.x * HID + c0];
        bf16x8 v3 = *(const bf16x8*)&hh[(size_t)p1.z * HID + c0];
        float w0 = __int_as_float(p0.y), w1 = __int_as_float(p0.w);
        float w2 = __int_as_float(p1.y), w3 = __int_as_float(p1.w);
#pragma unroll
        for (int j = 0; j < 8; ++j) {
            a[j] += (float)v0[j] * w0 + (float)v1[j] * w1
                  + (float)v2[j] * w2 + (float)v3[j] * w3;
        }
    }
    for (; e < e1; ++e) {
        int2 ed = epk[e];
        float w = __int_as_float(ed.y);
        bf16x8 v = *(const bf16x8*)&hh[(size_t)ed.x * HID + c0];
#pragma unroll
        for (int j = 0; j < 8; ++j) a[j] += (float)v[j] * w;
    }
#pragma unroll
    for (int j = 0; j < 8; ++j) {
        a[j] += bias[c0 + j];
        if (a[j] < 0.f) a[j] = 0.f;
    }

    if (LAST) {
        f32x4 o0 = {a[0], a[1], a[2], a[3]};
        f32x4 o1 = {a[4], a[5], a[6], a[7]};
        *(f32x4*)&x3[(size_t)node * HID + c0]     = o0;
        *(f32x4*)&x3[(size_t)node * HID + c0 + 4] = o1;
    } else {
        bf16x8 hi, lo;
#pragma unroll
        for (int j = 0; j < 8; ++j) {
            bf16_t hb = (bf16_t)a[j];
            hi[j] = hb;
            lo[j] = (bf16_t)(a[j] - (float)hb);
        }
        *(bf16x8*)&xh[(size_t)node * HID + c0] = hi;
        *(bf16x8*)&xl[(size_t)node * HID + c0] = lo;
    }
}

// ---------------------------------------------------------------------------
// Pooling: pooled[g][c] += x3[n][c] for batch[n]==g (batch sorted, run-flush)
// ---------------------------------------------------------------------------
__global__ void pool_k(const float* __restrict__ x3, const int* __restrict__ batch,
                       float* __restrict__ pooled) {
    int t  = threadIdx.x;            // 256: cols t and t+256
    int n0 = blockIdx.x * 20;
    int nend = min(n0 + 20, N_NODES);
    float acc0 = 0.f, acc1 = 0.f;
    int cur = -1;
    for (int n = n0; n < nend; ++n) {
        int g = batch[n];
        if (g != cur) {
            if (cur >= 0) {
                atomicAdd(&pooled[cur * HID + t], acc0);
                atomicAdd(&pooled[cur * HID + t + 256], acc1);
            }
            cur = g; acc0 = 0.f; acc1 = 0.f;
        }
        acc0 += x3[(size_t)n * HID + t];
        acc1 += x3[(size_t)n * HID + t + 256];
    }
    if (cur >= 0) {
        atomicAdd(&pooled[cur * HID + t], acc0);
        atomicAdd(&pooled[cur * HID + t + 256], acc1);
    }
}

// ---------------------------------------------------------------------------
// Head: logits = pooled @ lin_w + lin_b ; log_softmax. One wave per graph.
// ---------------------------------------------------------------------------
__global__ __launch_bounds__(64) void head_k(const float* __restrict__ pooled,
                                             const float* __restrict__ lw,
                                             const float* __restrict__ lb,
                                             float* __restrict__ out) {
    int g = blockIdx.x, l = threadIdx.x;
    float lg[10];
#pragma unroll
    for (int c = 0; c < N_CLASSES; ++c) {
        float s = 0.f;
        for (int k = l; k < HID; k += 64) s += pooled[g * HID + k] * lw[k * N_CLASSES + c];
        for (int o2 = 32; o2 > 0; o2 >>= 1) s += __shfl_down(s, o2);
        lg[c] = s;
    }
    if (l == 0) {
        float mx = -1e30f;
#pragma unroll
        for (int c = 0; c < N_CLASSES; ++c) { lg[c] += lb[c]; mx = fmaxf(mx, lg[c]); }
        float se = 0.f;
#pragma unroll
        for (int c = 0; c < N_CLASSES; ++c) se += expf(lg[c] - mx);
        float lse = logf(se);
#pragma unroll
        for (int c = 0; c < N_CLASSES; ++c) out[g * N_CLASSES + c] = lg[c] - mx - lse;
    }
}

// ---------------------------------------------------------------------------
extern "C" void kernel_launch(void* const* d_in, const int* in_sizes, int n_in,
                              void* d_out, int out_size, void* d_ws, size_t ws_size,
                              hipStream_t stream) {
    const float* x     = (const float*)d_in[0];
    const int*   ei    = (const int*)d_in[1];
    const int*   batch = (const int*)d_in[2];
    const float* Ws    = (const float*)d_in[3];
    const float* bs    = (const float*)d_in[4];
    const float* lw    = (const float*)d_in[5];
    const float* lb    = (const float*)d_in[6];
    float*       out   = (float*)d_out;
    const int E = in_sizes[1] / 2;
    const int* erow = ei;       // edge_index[0] = source
    const int* ecol = ei + E;   // edge_index[1] = target (aggregation index)

    char* p = (char*)d_ws;
    auto take = [&](size_t bytes) {
        char* q = p;
        p += (bytes + 255) & ~(size_t)255;
        return q;
    };
    bf16_t* xh    = (bf16_t*)take((size_t)MPAD * HID * 2);
    bf16_t* xl    = (bf16_t*)take((size_t)MPAD * HID * 2);
    bf16_t* hh    = (bf16_t*)take((size_t)MPAD * HID * 2);
    float*  x3    = (float*) take((size_t)N_NODES * HID * 4);
    bf16_t* whT   = (bf16_t*)take((size_t)3 * HID * HID * 2);
    float*  dinv  = (float*) take((size_t)N_NODES * 4);
    int*    cnt   = (int*)   take((size_t)N_NODES * 4);
    int*    off   = (int*)   take((size_t)(N_NODES + 1) * 4);
    int*    cur   = (int*)   take((size_t)N_NODES * 4);
    int2*   epk   = (int2*)  take((size_t)E * 8 + 16);   // +pad for int4 tail read
    float*  pooled= (float*) take((size_t)N_GRAPHS * HID * 4);

    const int cdeg_b = (E + 255) / 256;
    zero_k<<<40, 256, 0, stream>>>(cnt, cur, xh + (size_t)N_NODES * HID,
                                   xl + (size_t)N_NODES * HID, pooled);
    setup_k<<<CVX_B + CVW_B + cdeg_b, 256, 0, stream>>>(
        x, xh, xl, Ws, whT, ecol, cnt, E);
    scan_k<<<1, 1024, 0, stream>>>(cnt, off, dinv);
    scatter_k<<<cdeg_b, 256, 0, stream>>>(erow, ecol, off, cur, dinv, epk, E);

    for (int lyr = 0; lyr < 3; ++lyr) {
        gemm3<<<dim3(4, 158), 256, 0, stream>>>(
            xh, xl, whT + (size_t)lyr * HID * HID, hh);
        if (lyr < 2)
            agg_k<false><<<(N_NODES + 3) / 4, 256, 0, stream>>>(
                hh, off, epk, dinv, bs + lyr * HID, xh, xl, nullptr);
        else
            agg_k<true><<<(N_NODES + 3) / 4, 256, 0, stream>>>(
                hh, off, epk, dinv, bs + lyr * HID, nullptr, nullptr, x3);
    }
    pool_k<<<500, 256, 0, stream>>>(x3, batch, pooled);
    head_k<<<N_GRAPHS, 64, 0, stream>>>(pooled, lw, lb, out);
}